// Round 2
// baseline (476.144 us; speedup 1.0000x reference)
//
#include <hip/hip_runtime.h>
#include <cstdint>
#include <cstddef>

// TSPEdgeEmbedding on MI355X.
// Outputs (flat float32 in d_out, in reference return order):
//   [0, 2048000)              x = init_embeddings passthrough [B*n, D]
//   [2048000, 2848000)        edge_index row 0 (src), as float
//   [2848000, 3648000)        edge_index row 1 (dst), as float
//   [3648000, 106048000)      edge_emb [B*n*k, D] = dist*W + b
//
// One wave (64 lanes) per node. Lane l owns candidates j = l + 64*s
// (strided => conflict-free LDS reads of float2).
//
// Keys: key = (f32_bits(dist) << 32) | j, bit-cast to double. dist >= 0
// => sign 0 => u64 bit order == double order; hi <= 0x7F800000 => always
// finite => fmin/fmax exact. Min over keys == (min dist, tie -> min j)
// == lax.top_k's stable tiebreak. Winner index = low 32 bits of the min.
//
// Each lane bitonic-sorts its 16 keys once. Extraction is 4 RANKS PER
// ROUND: each lane feeds its sorted head-quad into a 6-step xor
// butterfly whose combine is a bitonic merge-4 (keep lowest 4). One
// chain of depth 6 yields the global smallest-4, sorted, in all lanes
// -> 13 dependency chains instead of 50 (latency was the bottleneck).
// Pop = shift own list left by c = #{own keys <= w3} (a prefix, since
// the list is sorted), done as three static masked shifts (c = 4,2,1
// bits). edge_emb rows 4r..4r+3 are stored inside round r, overlapping
// stores with the reduction latency chain.

namespace {

constexpr int kB  = 16;
constexpr int kN  = 1000;
constexpr int kD  = 128;
constexpr int kK  = 50;
constexpr int kCPL = 16;                               // candidates per lane (64*16 = 1024 >= 1000)
constexpr int kNodesPerBlock = 4;                      // 4 waves / 256-thread block
constexpr int kBlocksPerBatch = kN / kNodesPerBlock;   // 250 (exact)
constexpr int kFullRounds = 12;                        // 12*4 = 48 ranks, then a 2-rank peel

__device__ __forceinline__ double pack_key(float dd, int j) {
  const unsigned long long u =
      ((unsigned long long)__float_as_uint(dd) << 32) | (unsigned)j;
  return __longlong_as_double((long long)u);
}

__device__ __forceinline__ float key_dist(double k) {
  const unsigned long long u = (unsigned long long)__double_as_longlong(k);
  return __uint_as_float((unsigned)(u >> 32));
}

__device__ __forceinline__ int key_idx(double k) {
  return (int)((unsigned long long)__double_as_longlong(k) & 0xFFFFFFFFull);
}

__global__ __launch_bounds__(256)
void tsp_edge_kernel(const float* __restrict__ locs,
                     const float* __restrict__ init_emb,
                     const float* __restrict__ W,
                     const float* __restrict__ bias,
                     float* __restrict__ out)
{
#pragma clang fp contract(off)   // match numpy/XLA: separate mul/add rounding, no FMA
  const int tid  = threadIdx.x;
  const int wave = tid >> 6;
  const int lane = tid & 63;
  const int blk  = blockIdx.x;
  const int b    = blk / kBlocksPerBatch;
  const int node_in_b = (blk % kBlocksPerBatch) * kNodesPerBlock + wave;
  const int node = b * kN + node_in_b;    // global node id (= src index)

  // ---- output geometry ----
  constexpr size_t X_SZ    = (size_t)kB * kN * kD;   // 2,048,000
  constexpr size_t E_SZ    = (size_t)kB * kN * kK;   // 800,000
  constexpr size_t SRC_OFF = X_SZ;
  constexpr size_t DST_OFF = X_SZ + E_SZ;
  constexpr size_t EMB_OFF = X_SZ + 2 * E_SZ;

  // ---- independent outputs first: overlap their traffic with selection ----
  // x passthrough: one row (128 floats) per wave, float2 per lane
  {
    const float2* srcp = reinterpret_cast<const float2*>(init_emb + (size_t)node * kD);
    float2* dstp = reinterpret_cast<float2*>(out + (size_t)node * kD);
    dstp[lane] = srcp[lane];
  }
  // edge_index src row (value independent of selection)
  if (lane < kK) {
    out[SRC_OFF + (size_t)node * kK + lane] = (float)node;
  }

  // ---- stage this batch's locs into LDS (shared by the 4 waves) ----
  __shared__ float2 sloc[kN];
  {
    const float4* gl4 = reinterpret_cast<const float4*>(locs + (size_t)b * kN * 2);
    float4* sl4 = reinterpret_cast<float4*>(sloc);
    for (int t = tid; t < kN / 2; t += 256) sl4[t] = gl4[t];
  }
  __syncthreads();

  const float2 my = sloc[node_in_b];

  // ---- per-lane candidate keys (registers), strided ownership ----
  double key[kCPL];
#pragma unroll
  for (int s = 0; s < kCPL; ++s) {
    const int j = lane + (s << 6);
    const bool valid = (j < kN) && (j != node_in_b);
    const float2 pj = sloc[(j < kN) ? j : 0];     // conflict-free: lanes consecutive
    const float dx = my.x - pj.x;
    const float dy = my.y - pj.y;
    const float d2 = dx * dx + dy * dy;           // contract(off): matches np bitwise
    float dd = sqrtf(d2 + 1e-12f);
    if (!valid) dd = INFINITY;                    // hi = 0x7F800000, still a finite double key
    key[s] = pack_key(dd, j);
  }

  // ---- one-time per-lane bitonic sort (ascending), 80 CE, all in VGPRs ----
#pragma unroll
  for (int kk = 2; kk <= kCPL; kk <<= 1) {
#pragma unroll
    for (int jj = kk >> 1; jj > 0; jj >>= 1) {
#pragma unroll
      for (int i = 0; i < kCPL; ++i) {
        const int l2 = i ^ jj;
        if (l2 > i) {
          const double a  = key[i];
          const double c  = key[l2];
          const double lo = fmin(a, c);
          const double hi = fmax(a, c);
          if ((i & kk) == 0) { key[i] = lo; key[l2] = hi; }
          else               { key[i] = hi; key[l2] = lo; }
        }
      }
    }
  }

  // per-lane Linear(1,D) coefficients: lane covers cols [2*lane, 2*lane+2)
  const float2 wv = reinterpret_cast<const float2*>(W)[lane];
  const float2 bv = reinterpret_cast<const float2*>(bias)[lane];
  float* ebase = out + EMB_OFF + (size_t)node * (kK * kD);
  const int col2 = lane * 2;

  int res_j = 0;   // lane r (< kK) ends holding rank-r neighbor index
  const double INFK = __builtin_inf();  // > every key; never equals one

  // ---- 12 rounds x 4 ranks + 2-rank peel ----
#pragma unroll 1
  for (int r = 0; r < kFullRounds; ++r) {
    // butterfly merge-4: after 6 steps every lane holds global smallest-4 asc
    double m0 = key[0], m1 = key[1], m2 = key[2], m3 = key[3];
#pragma unroll
    for (int st = 1; st < 64; st <<= 1) {
      const double t0 = __shfl_xor(m0, st, 64);
      const double t1 = __shfl_xor(m1, st, 64);
      const double t2 = __shfl_xor(m2, st, 64);
      const double t3 = __shfl_xor(m3, st, 64);
      // lower half of bitonic merge (asc m ++ desc t)
      const double c0 = fmin(m0, t3);
      const double c1 = fmin(m1, t2);
      const double c2 = fmin(m2, t1);
      const double c3 = fmin(m3, t0);
      // clean the 4-element bitonic sequence: stride 2, then stride 1
      const double d0 = fmin(c0, c2), d2 = fmax(c0, c2);
      const double d1 = fmin(c1, c3), d3 = fmax(c1, c3);
      m0 = fmin(d0, d1); m1 = fmax(d0, d1);
      m2 = fmin(d2, d3); m3 = fmax(d2, d3);
    }

    // record neighbor indices at their rank lanes
    const int r4 = 4 * r;
    if (lane == r4    ) res_j = key_idx(m0);
    if (lane == r4 + 1) res_j = key_idx(m1);
    if (lane == r4 + 2) res_j = key_idx(m2);
    if (lane == r4 + 3) res_j = key_idx(m3);

    // fused edge_emb stores: rows 4r..4r+3, float2 per lane per row
    {
      const float a0 = key_dist(m0), a1 = key_dist(m1);
      const float a2 = key_dist(m2), a3 = key_dist(m3);
      float* rp = ebase + (size_t)r4 * kD + col2;
      float2 v;
      v.x = a0 * wv.x + bv.x;  v.y = a0 * wv.y + bv.y;
      *reinterpret_cast<float2*>(rp) = v;
      v.x = a1 * wv.x + bv.x;  v.y = a1 * wv.y + bv.y;
      *reinterpret_cast<float2*>(rp + kD) = v;
      v.x = a2 * wv.x + bv.x;  v.y = a2 * wv.y + bv.y;
      *reinterpret_cast<float2*>(rp + 2 * kD) = v;
      v.x = a3 * wv.x + bv.x;  v.y = a3 * wv.y + bv.y;
      *reinterpret_cast<float2*>(rp + 3 * kD) = v;
    }

    // pop: this lane lost c = #{key[i] <= w3} elements, a prefix of its
    // sorted list (winners are the global smallest-4). Shift left by c.
    const double w3 = m3;
    const int c = (key[0] <= w3 ? 1 : 0) + (key[1] <= w3 ? 1 : 0) +
                  (key[2] <= w3 ? 1 : 0) + (key[3] <= w3 ? 1 : 0);
    if (c & 4) {
#pragma unroll
      for (int s = 0; s < kCPL - 4; ++s) key[s] = key[s + 4];
      key[12] = INFK; key[13] = INFK; key[14] = INFK; key[15] = INFK;
    }
    if (c & 2) {
#pragma unroll
      for (int s = 0; s < kCPL - 2; ++s) key[s] = key[s + 2];
      key[14] = INFK; key[15] = INFK;
    }
    if (c & 1) {
#pragma unroll
      for (int s = 0; s < kCPL - 1; ++s) key[s] = key[s + 1];
      key[15] = INFK;
    }
  }

  // ---- peel: ranks 48, 49 (one butterfly, no pop) ----
  {
    double m0 = key[0], m1 = key[1], m2 = key[2], m3 = key[3];
#pragma unroll
    for (int st = 1; st < 64; st <<= 1) {
      const double t0 = __shfl_xor(m0, st, 64);
      const double t1 = __shfl_xor(m1, st, 64);
      const double t2 = __shfl_xor(m2, st, 64);
      const double t3 = __shfl_xor(m3, st, 64);
      const double c0 = fmin(m0, t3);
      const double c1 = fmin(m1, t2);
      const double c2 = fmin(m2, t1);
      const double c3 = fmin(m3, t0);
      const double d0 = fmin(c0, c2), d2 = fmax(c0, c2);
      const double d1 = fmin(c1, c3), d3 = fmax(c1, c3);
      m0 = fmin(d0, d1); m1 = fmax(d0, d1);
      m2 = fmin(d2, d3); m3 = fmax(d2, d3);
    }
    if (lane == 48) res_j = key_idx(m0);
    if (lane == 49) res_j = key_idx(m1);

    const float a0 = key_dist(m0), a1 = key_dist(m1);
    float* rp = ebase + (size_t)48 * kD + col2;
    float2 v;
    v.x = a0 * wv.x + bv.x;  v.y = a0 * wv.y + bv.y;
    *reinterpret_cast<float2*>(rp) = v;
    v.x = a1 * wv.x + bv.x;  v.y = a1 * wv.y + bv.y;
    *reinterpret_cast<float2*>(rp + kD) = v;
  }

  // ---- edge_index dst (float values; max 15999 exact in f32) ----
  if (lane < kK) {
    out[DST_OFF + (size_t)node * kK + lane] = (float)(b * kN + res_j);
  }
}

} // namespace

extern "C" void kernel_launch(void* const* d_in, const int* in_sizes, int n_in,
                              void* d_out, int out_size, void* d_ws, size_t ws_size,
                              hipStream_t stream) {
  const float* locs = (const float*)d_in[0];   // [16,1000,2]
  const float* emb  = (const float*)d_in[1];   // [16,1000,128]
  const float* W    = (const float*)d_in[2];   // [1,128]
  const float* bias = (const float*)d_in[3];   // [128]
  float* out = (float*)d_out;

  dim3 grid(kB * kBlocksPerBatch);   // 4000 blocks = 16000 waves = 1 per node
  dim3 block(256);
  hipLaunchKernelGGL(tsp_edge_kernel, grid, block, 0, stream, locs, emb, W, bias, out);
}

// Round 4
// 445.591 us; speedup vs baseline: 1.0686x; 1.0686x over previous
//
#include <hip/hip_runtime.h>
#include <cstdint>
#include <cstddef>

// TSPEdgeEmbedding on MI355X.  (R3 resubmit -- previous bench run died on
// container acquisition, not on the kernel.)
// Outputs (flat float32 in d_out, in reference return order):
//   [0, 2048000)              x = init_embeddings passthrough [B*n, D]
//   [2048000, 2848000)        edge_index row 0 (src), as float
//   [2848000, 3648000)        edge_index row 1 (dst), as float
//   [3648000, 106048000)      edge_emb [B*n*k, D] = dist*W + b
//
// One wave (64 lanes) per node. Lane l owns candidates j = l + 64*s
// (strided => conflict-free LDS reads of float2).
//
// R2 post-mortem: selection was DS-pipe-bound (~620 ds_bpermute per wave
// for the shuffle butterflies ~= 97 us of per-CU DS serialization).
// R3 moves the wave-min OFF the DS pipe:
//   strides 1-8 : DPP (quad_perm xor1/xor2, row_half_mirror, row_mirror)
//                 fused with v_min_u32 -- VALU pipe only.
//   strides 16/32: v_readlane lanes {0,16,32,48} + s_min_u32 (SALU).
//                 dist >= 0 => f32 bit order == u32 order.
//   winner j    : ballot + readlane at the lowest matching lane; exact
//                 dist ties (must pick lowest j, matching lax.top_k's
//                 stable order) fall into a rare scalar loop over the
//                 ballot mask. A lane's equal-dist heads are already in
//                 j-order (per-lane list sorted by packed (dist,j) key),
//                 so head-only comparison is exact.
// Per-round DS ops: 12 -> 0. Stores (67 us HBM floor) become the limit.
//
// Keys: key = (f32_bits(dist) << 32) | j, bit-cast to double (sign 0,
// exponent < 0x7FF => finite => fmin/fmax exact). One-time per-lane
// bitonic sort of 16 keys; pop = 1-lane cndmask shift; head = key[0].
// edge_emb row r is stored inside round r (stores overlap selection).

namespace {

constexpr int kB  = 16;
constexpr int kN  = 1000;
constexpr int kD  = 128;
constexpr int kK  = 50;
constexpr int kCPL = 16;                               // candidates per lane (64*16 = 1024 >= 1000)
constexpr int kNodesPerBlock = 4;                      // 4 waves / 256-thread block
constexpr int kBlocksPerBatch = kN / kNodesPerBlock;   // 250 (exact)

__device__ __forceinline__ double pack_key(float dd, int j) {
  const unsigned long long u =
      ((unsigned long long)__float_as_uint(dd) << 32) | (unsigned)j;
  return __longlong_as_double((long long)u);
}

// min over self and DPP-permuted self (stays on the VALU pipe)
template<int CTRL>
__device__ __forceinline__ unsigned dpp_min_u32(unsigned x) {
  const unsigned y = (unsigned)__builtin_amdgcn_update_dpp(
      0, (int)x, CTRL, 0xF, 0xF, true);
  return x < y ? x : y;
}

__global__ __launch_bounds__(256)
void tsp_edge_kernel(const float* __restrict__ locs,
                     const float* __restrict__ init_emb,
                     const float* __restrict__ W,
                     const float* __restrict__ bias,
                     float* __restrict__ out)
{
#pragma clang fp contract(off)   // match numpy/XLA: separate mul/add rounding, no FMA
  const int tid  = threadIdx.x;
  const int wave = tid >> 6;
  const int lane = tid & 63;
  const int blk  = blockIdx.x;
  const int b    = blk / kBlocksPerBatch;
  const int node_in_b = (blk % kBlocksPerBatch) * kNodesPerBlock + wave;
  const int node = b * kN + node_in_b;    // global node id (= src index)

  // ---- output geometry ----
  constexpr size_t X_SZ    = (size_t)kB * kN * kD;   // 2,048,000
  constexpr size_t E_SZ    = (size_t)kB * kN * kK;   // 800,000
  constexpr size_t SRC_OFF = X_SZ;
  constexpr size_t DST_OFF = X_SZ + E_SZ;
  constexpr size_t EMB_OFF = X_SZ + 2 * E_SZ;

  // ---- independent outputs first: overlap their traffic with selection ----
  {
    const float2* srcp = reinterpret_cast<const float2*>(init_emb + (size_t)node * kD);
    float2* dstp = reinterpret_cast<float2*>(out + (size_t)node * kD);
    dstp[lane] = srcp[lane];
  }
  if (lane < kK) {
    out[SRC_OFF + (size_t)node * kK + lane] = (float)node;
  }

  // ---- stage this batch's locs into LDS (shared by the 4 waves) ----
  __shared__ __align__(16) float2 sloc[kN];
  {
    const float4* gl4 = reinterpret_cast<const float4*>(locs + (size_t)b * kN * 2);
    float4* sl4 = reinterpret_cast<float4*>(sloc);
    for (int t = tid; t < kN / 2; t += 256) sl4[t] = gl4[t];
  }
  __syncthreads();

  const float2 my = sloc[node_in_b];

  // ---- per-lane candidate keys (registers), strided ownership ----
  double key[kCPL];
#pragma unroll
  for (int s = 0; s < kCPL; ++s) {
    const int j = lane + (s << 6);
    const bool valid = (j < kN) && (j != node_in_b);
    const float2 pj = sloc[(j < kN) ? j : 0];     // conflict-free: lanes consecutive
    const float dx = my.x - pj.x;
    const float dy = my.y - pj.y;
    const float d2 = dx * dx + dy * dy;           // contract(off): matches np bitwise
    float dd = sqrtf(d2 + 1e-12f);
    if (!valid) dd = INFINITY;                    // hi = 0x7F800000, still a finite double key
    key[s] = pack_key(dd, j);
  }

  // ---- one-time per-lane bitonic sort (ascending), 80 CE, all in VGPRs ----
#pragma unroll
  for (int kk = 2; kk <= kCPL; kk <<= 1) {
#pragma unroll
    for (int jj = kk >> 1; jj > 0; jj >>= 1) {
#pragma unroll
      for (int i = 0; i < kCPL; ++i) {
        const int l2 = i ^ jj;
        if (l2 > i) {
          const double a  = key[i];
          const double c  = key[l2];
          const double lo = fmin(a, c);
          const double hi = fmax(a, c);
          if ((i & kk) == 0) { key[i] = lo; key[l2] = hi; }
          else               { key[i] = hi; key[l2] = lo; }
        }
      }
    }
  }

  // per-lane Linear(1,D) coefficients: lane covers cols [2*lane, 2*lane+2)
  const float2 wv = reinterpret_cast<const float2*>(W)[lane];
  const float2 bv = reinterpret_cast<const float2*>(bias)[lane];
  float* erow = out + EMB_OFF + (size_t)node * (kK * kD) + lane * 2;

  int res_j = 0;                         // lane r (< kK) ends holding rank-r index
  const double INFK = __builtin_inf();   // > every key; never equals one

  // ---- 50 extraction rounds, zero DS ops per round ----
#pragma unroll 1
  for (int r = 0; r < kK; ++r) {
    const unsigned long long u0 = (unsigned long long)__double_as_longlong(key[0]);
    const unsigned head_d = (unsigned)(u0 >> 32);   // f32 dist bits (>= 0)
    const unsigned head_j = (unsigned)u0;

    // wave-min of head_d: 4 DPP steps (VALU) -> per-16-row min in all lanes
    unsigned v = head_d;
    v = dpp_min_u32<0xB1>(v);    // quad_perm [1,0,3,2]  (xor 1)
    v = dpp_min_u32<0x4E>(v);    // quad_perm [2,3,0,1]  (xor 2)
    v = dpp_min_u32<0x141>(v);   // row_half_mirror      (xor 4 at group level)
    v = dpp_min_u32<0x140>(v);   // row_mirror           (xor 8 at group level)
    // rows -> wave via readlane + scalar min (u32 order == f32 order, d >= 0)
    const unsigned q0 = (unsigned)__builtin_amdgcn_readlane((int)v, 0);
    const unsigned q1 = (unsigned)__builtin_amdgcn_readlane((int)v, 16);
    const unsigned q2 = (unsigned)__builtin_amdgcn_readlane((int)v, 32);
    const unsigned q3 = (unsigned)__builtin_amdgcn_readlane((int)v, 48);
    const unsigned qa = q0 < q1 ? q0 : q1;
    const unsigned qb = q2 < q3 ? q2 : q3;
    const unsigned mu = qa < qb ? qa : qb;          // wave-uniform (SGPR)

    // winner index: lowest matching lane; exact dist-tie -> min j (rare)
    const unsigned long long msk = __ballot(head_d == mu);
    unsigned jwin = (unsigned)__builtin_amdgcn_readlane(
        (int)head_j, __ffsll((long long)msk) - 1);
    if (__popcll(msk) > 1) {
      unsigned long long mm = msk;
      jwin = 0xFFFFFFFFu;
      while (mm) {
        const int l = __ffsll((long long)mm) - 1;
        const unsigned jj = (unsigned)__builtin_amdgcn_readlane((int)head_j, l);
        jwin = jj < jwin ? jj : jwin;
        mm &= mm - 1;
      }
    }

    if (lane == r) res_j = (int)jwin;

    // fused edge_emb store: row r, float2 per lane (512 B coalesced / wave)
    const float dist = __uint_as_float(mu);
    float2 vv;
    vv.x = dist * wv.x + bv.x;
    vv.y = dist * wv.y + bv.y;
    *reinterpret_cast<float2*>(erow) = vv;
    erow += kD;

    // pop: exactly one lane's head equals (mu, jwin) -- shift its list
    const unsigned long long wk = ((unsigned long long)mu << 32) | jwin;
    const bool pop = (u0 == wk);
#pragma unroll
    for (int s = 0; s < kCPL - 1; ++s) key[s] = pop ? key[s + 1] : key[s];
    key[kCPL - 1] = pop ? INFK : key[kCPL - 1];
  }

  // ---- edge_index dst (float values; max 15999 exact in f32) ----
  if (lane < kK) {
    out[DST_OFF + (size_t)node * kK + lane] = (float)(b * kN + res_j);
  }
}

} // namespace

extern "C" void kernel_launch(void* const* d_in, const int* in_sizes, int n_in,
                              void* d_out, int out_size, void* d_ws, size_t ws_size,
                              hipStream_t stream) {
  const float* locs = (const float*)d_in[0];   // [16,1000,2]
  const float* emb  = (const float*)d_in[1];   // [16,1000,128]
  const float* W    = (const float*)d_in[2];   // [1,128]
  const float* bias = (const float*)d_in[3];   // [128]
  float* out = (float*)d_out;

  dim3 grid(kB * kBlocksPerBatch);   // 4000 blocks = 16000 waves = 1 per node
  dim3 block(256);
  hipLaunchKernelGGL(tsp_edge_kernel, grid, block, 0, stream, locs, emb, W, bias, out);
}